// Round 1
// baseline (195.334 us; speedup 1.0000x reference)
//
#include <hip/hip_runtime.h>
#include <stdint.h>

#define BATCH 32768

typedef __attribute__((ext_vector_type(8))) short short8;
typedef __attribute__((ext_vector_type(4))) float f32x4;

__device__ __forceinline__ uint16_t bf16_rtne(float f) {
    union { float f; uint32_t u; } v; v.f = f;
    uint32_t u = v.u;
    u += 0x7fffu + ((u >> 16) & 1u);
    return (uint16_t)(u >> 16);
}

__device__ __forceinline__ float fast_tanh(float x) {
    // tanh(x) = 1 - 2/(1+exp(2x)); exp2-based, saturates correctly at +/-inf
    float e = exp2f(x * 2.8853900817779268f);
    return 1.0f - 2.0f * __builtin_amdgcn_rcpf(1.0f + e);
}

__device__ __forceinline__ void async_load16(const void* g, void* l) {
    __builtin_amdgcn_global_load_lds(
        (const __attribute__((address_space(1))) unsigned int*)g,
        (__attribute__((address_space(3))) unsigned int*)l, 16, 0, 0);
}

// ---------- kernel 1: pack B = W2g (K=4096 x N=64) into bf16, MFMA-frag order ----------
// W2g[k][n] = sum_o W2[k*64+o] * Wg1[(d*64+o)*64+n],  d = k>>6
// packed flat index: (((ks*4 + nt)*64 + lane)*8 + j) with k = ks*32 + (lane>>4)*8 + j,
//                    n = nt*16 + (lane&15)  -> matches global_load_lds(lane*16B) staging.
__global__ void kol_pack_b(const float* __restrict__ W2, const float* __restrict__ Wg1,
                           uint16_t* __restrict__ Bp) {
    int t = threadIdx.x;
    int kl = t >> 6, n = t & 63;
    int k = blockIdx.x * 4 + kl;
    int d = k >> 6;
    const float* w2row = W2 + (size_t)k * 64;
    const float* g = Wg1 + (size_t)d * 4096 + n;
    float acc = 0.f;
#pragma unroll 8
    for (int o = 0; o < 64; ++o)
        acc = fmaf(w2row[o], g[(size_t)o * 64], acc);
    int ks = k >> 5, kk = k & 31;
    int quad = kk >> 3, j = kk & 7;
    int nt = n >> 4, lane = quad * 16 + (n & 15);
    Bp[(((size_t)(ks * 4 + nt)) * 64 + lane) * 8 + j] = bf16_rtne(acc);
}

// ---------- kernel 2: cg[n] = bg1[n] + sum_m b2[m]*Wg1[m*64+n]  (m over 4096) ----------
__global__ void kol_cg(const float* __restrict__ b2, const float* __restrict__ Wg1,
                       const float* __restrict__ bg1, float* __restrict__ cg) {
    __shared__ float red[4][64];
    int t = threadIdx.x;
    int n = t & 63, seg = t >> 6;
    float acc = 0.f;
    int m0 = seg * 1024;
#pragma unroll 4
    for (int m = m0; m < m0 + 1024; ++m)
        acc = fmaf(b2[m], Wg1[(size_t)m * 64 + n], acc);
    red[seg][n] = acc;
    __syncthreads();
    if (t < 64) cg[n] = bg1[n] + red[0][n] + red[1][n] + red[2][n] + red[3][n];
}

// ---------- kernel 3: main fused GEMM ----------
// C[32768 x 64] = H @ Bp, H generated in-register; epilogue reduces each row to out[b].
__global__ __launch_bounds__(256, 2) void kol_main(
    const float* __restrict__ x, const float* __restrict__ W1, const float* __restrict__ b1,
    const uint16_t* __restrict__ Bp, const float* __restrict__ cg,
    const float* __restrict__ Wg2, const float* __restrict__ bg2f,
    float* __restrict__ out) {
    __shared__ __align__(16) float xs[64 * 68];      // 64 rows, stride 68 (2-way max = free)
    __shared__ __align__(16) float w1s[4096];
    __shared__ __align__(16) float b1s[4096];
    __shared__ __align__(16) uint16_t bstage[4 * 512];  // 4KB: one 32x64 bf16 B tile

    const int tid = threadIdx.x;
    const int wave = tid >> 6, lane = tid & 63;
    const int quad = lane >> 4, lm = lane & 15;
    const int rowbase = blockIdx.x * 64;

    // cooperative staging: W1, b1 (4096 floats each), x tile (64x64)
    for (int i = tid * 4; i < 4096; i += 1024) {
        *(float4*)(&w1s[i]) = *(const float4*)(&W1[i]);
        *(float4*)(&b1s[i]) = *(const float4*)(&b1[i]);
        int r = i >> 6, c = i & 63;
        *(float4*)(&xs[r * 68 + c]) = *(const float4*)(&x[(size_t)(rowbase + r) * 64 + c]);
    }
    __syncthreads();

    f32x4 acc[4];
#pragma unroll
    for (int nt = 0; nt < 4; ++nt) acc[nt] = (f32x4){0.f, 0.f, 0.f, 0.f};

    const int myrow = wave * 16 + lm;

    for (int ks = 0; ks < 128; ++ks) {
        // stage this K-step's B tile: each wave DMAs one 1KB chunk (async)
        async_load16(Bp + ((size_t)(ks * 4 + wave) * 64 + lane) * 8,
                     &bstage[wave * 512]);

        // build A fragment in registers while the DMA is in flight
        const int d = ks >> 1, jh = ks & 1;
        const float xv = xs[myrow * 68 + d];
        const float* w1p = &w1s[d * 64 + jh * 32 + quad * 8];
        const float* b1p = &b1s[d * 64 + jh * 32 + quad * 8];
        short8 af;
#pragma unroll
        for (int j = 0; j < 8; ++j) {
            float h = fast_tanh(fmaf(xv, w1p[j], b1p[j]));
            af[j] = (short)bf16_rtne(h);
        }

        __syncthreads();  // B tile visible (drains vmcnt per m97 pattern)

        short8 bf0 = *(const short8*)&bstage[0 * 512 + lane * 8];
        short8 bf1 = *(const short8*)&bstage[1 * 512 + lane * 8];
        short8 bf2 = *(const short8*)&bstage[2 * 512 + lane * 8];
        short8 bf3 = *(const short8*)&bstage[3 * 512 + lane * 8];
        acc[0] = __builtin_amdgcn_mfma_f32_16x16x32_bf16(af, bf0, acc[0], 0, 0, 0);
        acc[1] = __builtin_amdgcn_mfma_f32_16x16x32_bf16(af, bf1, acc[1], 0, 0, 0);
        acc[2] = __builtin_amdgcn_mfma_f32_16x16x32_bf16(af, bf2, acc[2], 0, 0, 0);
        acc[3] = __builtin_amdgcn_mfma_f32_16x16x32_bf16(af, bf3, acc[3], 0, 0, 0);

        __syncthreads();  // protect bstage before next iteration's DMA
    }

    // epilogue: out[b] = bg2 + sum_n Wg2[n] * tanh(C[b,n] + cg[n])
    float wg2v[4], cgv[4];
#pragma unroll
    for (int nt = 0; nt < 4; ++nt) {
        wg2v[nt] = Wg2[nt * 16 + lm];
        cgv[nt]  = cg[nt * 16 + lm];
    }
    const float bg2 = bg2f[0];
#pragma unroll
    for (int r = 0; r < 4; ++r) {
        float s = 0.f;
#pragma unroll
        for (int nt = 0; nt < 4; ++nt)
            s += wg2v[nt] * fast_tanh(acc[nt][r] + cgv[nt]);
        // reduce across the 16 lanes of this quad-group (cols)
        s += __shfl_xor(s, 1, 64);
        s += __shfl_xor(s, 2, 64);
        s += __shfl_xor(s, 4, 64);
        s += __shfl_xor(s, 8, 64);
        if (lm == 0) {
            int row = rowbase + wave * 16 + quad * 4 + r;
            out[row] = s + bg2;
        }
    }
}

extern "C" void kernel_launch(void* const* d_in, const int* in_sizes, int n_in,
                              void* d_out, int out_size, void* d_ws, size_t ws_size,
                              hipStream_t stream) {
    const float* x   = (const float*)d_in[0];
    const float* W1  = (const float*)d_in[1];
    const float* b1  = (const float*)d_in[2];
    const float* W2  = (const float*)d_in[3];
    const float* b2  = (const float*)d_in[4];
    const float* Wg1 = (const float*)d_in[5];
    const float* bg1 = (const float*)d_in[6];
    const float* Wg2 = (const float*)d_in[7];
    const float* bg2 = (const float*)d_in[8];
    float* out = (float*)d_out;

    uint16_t* Bp = (uint16_t*)d_ws;                       // 4096*64 bf16 = 512KB
    float* cg = (float*)((char*)d_ws + 4096 * 64 * 2);    // 64 floats

    kol_pack_b<<<1024, 256, 0, stream>>>(W2, Wg1, Bp);
    kol_cg<<<1, 256, 0, stream>>>(b2, Wg1, bg1, cg);
    kol_main<<<BATCH / 64, 256, 0, stream>>>(x, W1, b1, Bp, cg, Wg2, bg2, out);
}

// Round 3
// 169.201 us; speedup vs baseline: 1.1544x; 1.1544x over previous
//
#include <hip/hip_runtime.h>
#include <stdint.h>

#define BATCH 32768

typedef __attribute__((ext_vector_type(8))) short short8;
typedef __attribute__((ext_vector_type(4))) float f32x4;
typedef __attribute__((ext_vector_type(4))) unsigned int u32x4;

__device__ __forceinline__ uint16_t bf16_rtne(float f) {
    union { float f; uint32_t u; } v; v.f = f;
    uint32_t u = v.u;
    u += 0x7fffu + ((u >> 16) & 1u);
    return (uint16_t)(u >> 16);
}

#if defined(__has_builtin)
#if __has_builtin(__builtin_amdgcn_cvt_pk_bf16_f32)
#define HAVE_CVT_PK_BF16 1
#endif
#endif

__device__ __forceinline__ uint32_t pack2_bf16(float a, float b) {
#ifdef HAVE_CVT_PK_BF16
    auto v = __builtin_amdgcn_cvt_pk_bf16_f32(a, b);
    uint32_t r; __builtin_memcpy(&r, &v, 4); return r;
#else
    return (uint32_t)bf16_rtne(a) | ((uint32_t)bf16_rtne(b) << 16);
#endif
}

__device__ __forceinline__ float fast_tanh(float x) {
    // tanh(x) = 1 - 2/(1+exp2(x*2/ln2)); native v_exp_f32 + v_rcp_f32
    float e = __builtin_amdgcn_exp2f(x * 2.8853900817779268f);
    return 1.0f - 2.0f * __builtin_amdgcn_rcpf(1.0f + e);
}

// ---------- kernel P: per-feature-d pack of B = W2g (bf16, MFMA frag order) ----------
// W2g[k=d*64+j][n] = sum_o W2[d,j,o] * Wg1[d*64+o, n]
// packed idx for (k,n): ks=k>>5, kk=k&31, quad=kk>>3, jj=kk&7,
//                       flat = ((ks*4+ng)*64 + quad*16 + (n&15))*8 + jj   (ng=n>>4)
__global__ __launch_bounds__(256) void kol_pack(const float* __restrict__ W2,
                                                const float* __restrict__ Wg1,
                                                uint16_t* __restrict__ Bp) {
    __shared__ __align__(16) float w2s[64 * 65];  // [j][o], stride 65
    __shared__ __align__(16) float g1s[64 * 64];  // [o][n]

    const int t = threadIdx.x;
    const int d = blockIdx.x;

    for (int f = t * 4; f < 4096; f += 1024) {
        float4 v = *(const float4*)&W2[(size_t)d * 4096 + f];
        int jj2 = f >> 6, oo = f & 63;
        float* w = &w2s[jj2 * 65 + oo];
        w[0] = v.x; w[1] = v.y; w[2] = v.z; w[3] = v.w;
        *(float4*)&g1s[f] = *(const float4*)&Wg1[(size_t)d * 4096 + f];
    }
    __syncthreads();

    const int j = t >> 2;       // k-row within d-block: 0..63
    const int ng = t & 3;       // n-quarter: 0..3
    float acc[16];
#pragma unroll
    for (int i = 0; i < 16; ++i) acc[i] = 0.f;

    const float* w2row = &w2s[j * 65];
#pragma unroll 4
    for (int o = 0; o < 64; ++o) {
        float w = w2row[o];
        const float* g = &g1s[o * 64 + ng * 16];
#pragma unroll
        for (int i = 0; i < 16; ++i) acc[i] = fmaf(w, g[i], acc[i]);
    }

    const int k = d * 64 + j;
    const int ks = k >> 5, kk = k & 31;
    const int quad = kk >> 3, jj = kk & 7;
    size_t base = (((size_t)(ks * 4 + ng)) * 64 + quad * 16) * 8 + jj;
#pragma unroll
    for (int i = 0; i < 16; ++i) Bp[base + (size_t)i * 8] = bf16_rtne(acc[i]);
}

// ---------- kernel C: cg[n] = bg1[n] + sum_m b2[m]*Wg1[m*64+n]  (m over 4096) ----------
// Single 1024-thread block, deterministic reduction order (no atomics).
__global__ __launch_bounds__(1024) void kol_cg(const float* __restrict__ b2,
                                               const float* __restrict__ Wg1,
                                               const float* __restrict__ bg1,
                                               float* __restrict__ cg) {
    __shared__ float red[16][64];
    const int t = threadIdx.x;
    const int n = t & 63, seg = t >> 6;
    float a = 0.f;
    const int m0 = seg * 256;
#pragma unroll 4
    for (int m = m0; m < m0 + 256; ++m)
        a = fmaf(b2[m], Wg1[(size_t)m * 64 + n], a);
    red[seg][n] = a;
    __syncthreads();
    if (t < 64) {
        float s = bg1[n];
#pragma unroll
        for (int r = 0; r < 16; ++r) s += red[r][n];
        cg[n] = s;
    }
}

// ---------- kernel M: main fused GEMM ----------
// 512 threads = 8 waves, 128 rows/block, 256 blocks -> 2 blocks/CU, 16 waves/CU.
// B staged in 32KB slices (256 k-values = 4 d = 8 K-steps) -> 32 barriers total.
// W1/b1 read directly from global (32KB total, L1/L2-resident, quad-broadcast).
__global__ __launch_bounds__(512, 4) void kol_main(
    const float* __restrict__ x, const float* __restrict__ W1, const float* __restrict__ b1,
    const uint16_t* __restrict__ Bp, const float* __restrict__ cg,
    const float* __restrict__ Wg2, const float* __restrict__ bg2f,
    float* __restrict__ out) {
    __shared__ __align__(16) float xs[128 * 68];        // 34816 B; stride 68 -> 2-way = free
    __shared__ __align__(16) uint16_t bsl[16384];       // 32768 B B-slice

    const int tid = threadIdx.x;
    const int wave = tid >> 6, lane = tid & 63;
    const int quad = lane >> 4, lm = lane & 15;
    const int rowbase = blockIdx.x * 128;

    for (int f = tid * 4; f < 8192; f += 2048) {
        int r = f >> 6, c = f & 63;
        *(float4*)(&xs[r * 68 + c]) = *(const float4*)(&x[(size_t)(rowbase + r) * 64 + c]);
    }

    f32x4 acc[4];
#pragma unroll
    for (int nt = 0; nt < 4; ++nt) acc[nt] = (f32x4){0.f, 0.f, 0.f, 0.f};

    const int myrow = wave * 16 + lm;
    const u32x4* bsrc = (const u32x4*)Bp;
    u32x4* bdst = (u32x4*)bsl;
    const uint16_t* brd = &bsl[lane * 8];

    __syncthreads();  // xs visible

    for (int stage = 0; stage < 16; ++stage) {
        // stage one 32KB B-slice: 2048 uint4, 512 threads x 4
#pragma unroll
        for (int r = 0; r < 4; ++r)
            bdst[tid + 512 * r] = bsrc[stage * 2048 + tid + 512 * r];
        __syncthreads();

#pragma unroll 2
        for (int p = 0; p < 4; ++p) {
            const int d = stage * 4 + p;
            const float xv = xs[myrow * 68 + d];
            const float* w1q = &W1[d * 64 + quad * 8];
            const float* b1q = &b1[d * 64 + quad * 8];
            float4 wA = *(const float4*)&w1q[0];
            float4 wB = *(const float4*)&w1q[4];
            float4 wC = *(const float4*)&w1q[32];
            float4 wD = *(const float4*)&w1q[36];
            float4 bA = *(const float4*)&b1q[0];
            float4 bB = *(const float4*)&b1q[4];
            float4 bC = *(const float4*)&b1q[32];
            float4 bD = *(const float4*)&b1q[36];

            union { short8 s; uint32_t u[4]; } a0, a1;
            a0.u[0] = pack2_bf16(fast_tanh(fmaf(xv, wA.x, bA.x)), fast_tanh(fmaf(xv, wA.y, bA.y)));
            a0.u[1] = pack2_bf16(fast_tanh(fmaf(xv, wA.z, bA.z)), fast_tanh(fmaf(xv, wA.w, bA.w)));
            a0.u[2] = pack2_bf16(fast_tanh(fmaf(xv, wB.x, bB.x)), fast_tanh(fmaf(xv, wB.y, bB.y)));
            a0.u[3] = pack2_bf16(fast_tanh(fmaf(xv, wB.z, bB.z)), fast_tanh(fmaf(xv, wB.w, bB.w)));
            a1.u[0] = pack2_bf16(fast_tanh(fmaf(xv, wC.x, bC.x)), fast_tanh(fmaf(xv, wC.y, bC.y)));
            a1.u[1] = pack2_bf16(fast_tanh(fmaf(xv, wC.z, bC.z)), fast_tanh(fmaf(xv, wC.w, bC.w)));
            a1.u[2] = pack2_bf16(fast_tanh(fmaf(xv, wD.x, bD.x)), fast_tanh(fmaf(xv, wD.y, bD.y)));
            a1.u[3] = pack2_bf16(fast_tanh(fmaf(xv, wD.z, bD.z)), fast_tanh(fmaf(xv, wD.w, bD.w)));

#pragma unroll
            for (int s = 0; s < 2; ++s) {
                short8 af = s ? a1.s : a0.s;
                const int ks = p * 2 + s;   // local K-step within slice
#pragma unroll
                for (int nt = 0; nt < 4; ++nt) {
                    short8 bf = *(const short8*)&brd[((ks * 4 + nt) * 64) * 8];
                    acc[nt] = __builtin_amdgcn_mfma_f32_16x16x32_bf16(af, bf, acc[nt], 0, 0, 0);
                }
            }
        }
        __syncthreads();  // protect bsl before next slice overwrite
    }

    // epilogue: out[b] = bg2 + sum_n Wg2[n] * tanh(C[b,n] + cg[n])   (cg includes bg1)
    float wg2v[4], cgv[4];
#pragma unroll
    for (int nt = 0; nt < 4; ++nt) {
        wg2v[nt] = Wg2[nt * 16 + lm];
        cgv[nt]  = cg[nt * 16 + lm];
    }
    const float bg2 = bg2f[0];
#pragma unroll
    for (int r = 0; r < 4; ++r) {
        float s = 0.f;
#pragma unroll
        for (int nt = 0; nt < 4; ++nt)
            s += wg2v[nt] * fast_tanh(acc[nt][r] + cgv[nt]);
        s += __shfl_xor(s, 1, 64);
        s += __shfl_xor(s, 2, 64);
        s += __shfl_xor(s, 4, 64);
        s += __shfl_xor(s, 8, 64);
        if (lm == 0) {
            int row = rowbase + wave * 16 + quad * 4 + r;
            out[row] = s + bg2;
        }
    }
}

extern "C" void kernel_launch(void* const* d_in, const int* in_sizes, int n_in,
                              void* d_out, int out_size, void* d_ws, size_t ws_size,
                              hipStream_t stream) {
    const float* x   = (const float*)d_in[0];
    const float* W1  = (const float*)d_in[1];
    const float* b1  = (const float*)d_in[2];
    const float* W2  = (const float*)d_in[3];
    const float* b2  = (const float*)d_in[4];
    const float* Wg1 = (const float*)d_in[5];
    const float* bg1 = (const float*)d_in[6];
    const float* Wg2 = (const float*)d_in[7];
    const float* bg2 = (const float*)d_in[8];
    float* out = (float*)d_out;

    // ws budget: 512KB (Bp) + 256B (cg) = 524544 B  (same as round-1-proven usage)
    uint16_t* Bp = (uint16_t*)d_ws;
    float* cg    = (float*)((char*)d_ws + 4096 * 64 * 2);

    kol_pack<<<64, 256, 0, stream>>>(W2, Wg1, Bp);
    kol_cg<<<1, 1024, 0, stream>>>(b2, Wg1, bg1, cg);
    kol_main<<<BATCH / 128, 512, 0, stream>>>(x, W1, b1, Bp, cg, Wg2, bg2, out);
}

// Round 4
// 150.629 us; speedup vs baseline: 1.2968x; 1.1233x over previous
//
#include <hip/hip_runtime.h>
#include <stdint.h>

#define BATCH 32768
#define TANH_C 2.8853900817779268f   // 2/ln(2)

typedef __attribute__((ext_vector_type(8))) short short8;
typedef __attribute__((ext_vector_type(4))) float f32x4;
typedef __attribute__((ext_vector_type(4))) unsigned int u32x4;

__device__ __forceinline__ uint16_t bf16_rtne(float f) {
    union { float f; uint32_t u; } v; v.f = f;
    uint32_t u = v.u;
    u += 0x7fffu + ((u >> 16) & 1u);
    return (uint16_t)(u >> 16);
}

#if defined(__has_builtin)
#if __has_builtin(__builtin_amdgcn_cvt_pk_bf16_f32)
#define HAVE_CVT_PK_BF16 1
#endif
#endif

__device__ __forceinline__ uint32_t pack2_bf16(float a, float b) {
#ifdef HAVE_CVT_PK_BF16
    auto v = __builtin_amdgcn_cvt_pk_bf16_f32(a, b);
    uint32_t r; __builtin_memcpy(&r, &v, 4); return r;
#else
    return (uint32_t)bf16_rtne(a) | ((uint32_t)bf16_rtne(b) << 16);
#endif
}

// input already scaled by TANH_C: tanh(x) with a = TANH_C*x
__device__ __forceinline__ float tanh_pre(float a) {
    float e = __builtin_amdgcn_exp2f(a);
    return 1.0f - 2.0f * __builtin_amdgcn_rcpf(1.0f + e);
}

__device__ __forceinline__ float fast_tanh(float x) {
    return tanh_pre(x * TANH_C);
}

// ---------- kernel P: per-feature-d pack of B = W2g (bf16, MFMA frag order) ----------
// W2g[k=d*64+j][n] = sum_o W2[d,j,o] * Wg1[d*64+o, n]
// Thread owns (jg = 8 consecutive j's quad-group, one n) -> ONE contiguous 16B store.
// flat 16B index: ((ks*4+nt)*64 + quad*16 + (n&15)) with ks=2d+(jg>>2), quad=jg&3, nt=n>>4.
__global__ __launch_bounds__(512) void kol_pack(const float* __restrict__ W2,
                                                const float* __restrict__ Wg1,
                                                uint16_t* __restrict__ Bp) {
    __shared__ __align__(16) float w2t[64 * 65];  // [o][j], stride 65
    __shared__ __align__(16) float g1s[64 * 64];  // [o][n]

    const int t = threadIdx.x;
    const int d = blockIdx.x;

    for (int f = t * 4; f < 4096; f += 2048) {
        float4 v = *(const float4*)&W2[(size_t)d * 4096 + f];
        int j = f >> 6, o = f & 63;   // W2[d][j][o..o+3]
        w2t[(o + 0) * 65 + j] = v.x;
        w2t[(o + 1) * 65 + j] = v.y;
        w2t[(o + 2) * 65 + j] = v.z;
        w2t[(o + 3) * 65 + j] = v.w;
        *(float4*)&g1s[f] = *(const float4*)&Wg1[(size_t)d * 4096 + f];
    }
    __syncthreads();

    const int jg = t >> 6;   // wave index = j-octet, wave-uniform
    const int n  = t & 63;
    float acc[8];
#pragma unroll
    for (int i = 0; i < 8; ++i) acc[i] = 0.f;

#pragma unroll 4
    for (int o = 0; o < 64; ++o) {
        float g = g1s[o * 64 + n];                 // conflict-free (2-way alias = free)
        const float* w = &w2t[o * 65 + jg * 8];    // wave-uniform broadcast, 2x b128
#pragma unroll
        for (int jj = 0; jj < 8; ++jj) acc[jj] = fmaf(w[jj], g, acc[jj]);
    }

    u32x4 pk;
    pk.x = pack2_bf16(acc[0], acc[1]);
    pk.y = pack2_bf16(acc[2], acc[3]);
    pk.z = pack2_bf16(acc[4], acc[5]);
    pk.w = pack2_bf16(acc[6], acc[7]);
    int off = ((d * 2 + (jg >> 2)) * 4 + (n >> 4)) * 64 + (jg & 3) * 16 + (n & 15);
    ((u32x4*)Bp)[off] = pk;   // contiguous 256B per 16-lane group
}

// ---------- kernel C: cg[n] = bg1[n] + sum_m b2[m]*Wg1[m*64+n]  (deterministic) ----------
__global__ __launch_bounds__(1024) void kol_cg(const float* __restrict__ b2,
                                               const float* __restrict__ Wg1,
                                               const float* __restrict__ bg1,
                                               float* __restrict__ cg) {
    __shared__ float red[16][64];
    const int t = threadIdx.x;
    const int n = t & 63, seg = t >> 6;
    float a = 0.f;
    const int m0 = seg * 256;
#pragma unroll 4
    for (int m = m0; m < m0 + 256; ++m)
        a = fmaf(b2[m], Wg1[(size_t)m * 64 + n], a);
    red[seg][n] = a;
    __syncthreads();
    if (t < 64) {
        float s = bg1[n];
#pragma unroll
        for (int r = 0; r < 16; ++r) s += red[r][n];
        cg[n] = s;
    }
}

// ---------- kernel M: main fused GEMM, NO K-loop barriers ----------
// 512 threads = 8 waves, 128 rows/block, 256 blocks (1 block/CU).
// B fragments loaded per-wave straight from L1/L2 (coalesced dwordx4); compiler
// prefetches across the tanh burst via vmcnt. W1/b1 in LDS (broadcast reads).
// x and b1 pre-scaled by TANH_C so the pre-exp multiply vanishes.
__global__ __launch_bounds__(512, 2) void kol_main(
    const float* __restrict__ x, const float* __restrict__ W1, const float* __restrict__ b1,
    const uint16_t* __restrict__ Bp, const float* __restrict__ cg,
    const float* __restrict__ Wg2, const float* __restrict__ bg2f,
    float* __restrict__ out) {
    __shared__ __align__(16) float xs[128 * 68];   // pre-scaled x, stride 68 (2-way = free)
    __shared__ __align__(16) float w1s[4096];
    __shared__ __align__(16) float b1s[4096];      // pre-scaled by TANH_C

    const int tid = threadIdx.x;
    const int wave = tid >> 6, lane = tid & 63;
    const int quad = lane >> 4, lm = lane & 15;
    const int rowbase = blockIdx.x * 128;

    for (int f = tid * 4; f < 8192; f += 2048) {
        int r = f >> 6, c = f & 63;
        float4 v = *(const float4*)&x[(size_t)(rowbase + r) * 64 + c];
        v.x *= TANH_C; v.y *= TANH_C; v.z *= TANH_C; v.w *= TANH_C;
        *(float4*)&xs[r * 68 + c] = v;
    }
    for (int f = tid * 4; f < 4096; f += 2048) {
        *(float4*)&w1s[f] = *(const float4*)&W1[f];
        float4 b = *(const float4*)&b1[f];
        b.x *= TANH_C; b.y *= TANH_C; b.z *= TANH_C; b.w *= TANH_C;
        *(float4*)&b1s[f] = b;
    }
    __syncthreads();   // the ONLY barrier

    f32x4 acc[4];
#pragma unroll
    for (int nt = 0; nt < 4; ++nt) acc[nt] = (f32x4){0.f, 0.f, 0.f, 0.f};

    const int myrow = wave * 16 + lm;
    const float* xrow = &xs[myrow * 68];
    const short8* bbase = (const short8*)Bp + lane;   // 16B-granular fragment stream

    for (int d = 0; d < 64; ++d) {
        // issue all 8 B-fragment loads for ks = 2d, 2d+1 first (prefetchable)
        const short8* bp = bbase + (size_t)d * 8 * 64;
        short8 bf[8];
#pragma unroll
        for (int i = 0; i < 8; ++i) bf[i] = bp[i * 64];

        // A fragments: 16 tanh in registers while loads are in flight
        const float xv = xrow[d];
        const float* wq = &w1s[d * 64 + quad * 8];
        const float* bq = &b1s[d * 64 + quad * 8];
        float4 wA = *(const float4*)&wq[0];
        float4 wB = *(const float4*)&wq[4];
        float4 wC = *(const float4*)&wq[32];
        float4 wD = *(const float4*)&wq[36];
        float4 bA = *(const float4*)&bq[0];
        float4 bB = *(const float4*)&bq[4];
        float4 bC = *(const float4*)&bq[32];
        float4 bD = *(const float4*)&bq[36];

        union { short8 s; uint32_t u[4]; } a0, a1;
        a0.u[0] = pack2_bf16(tanh_pre(fmaf(xv, wA.x, bA.x)), tanh_pre(fmaf(xv, wA.y, bA.y)));
        a0.u[1] = pack2_bf16(tanh_pre(fmaf(xv, wA.z, bA.z)), tanh_pre(fmaf(xv, wA.w, bA.w)));
        a0.u[2] = pack2_bf16(tanh_pre(fmaf(xv, wB.x, bB.x)), tanh_pre(fmaf(xv, wB.y, bB.y)));
        a0.u[3] = pack2_bf16(tanh_pre(fmaf(xv, wB.z, bB.z)), tanh_pre(fmaf(xv, wB.w, bB.w)));
        a1.u[0] = pack2_bf16(tanh_pre(fmaf(xv, wC.x, bC.x)), tanh_pre(fmaf(xv, wC.y, bC.y)));
        a1.u[1] = pack2_bf16(tanh_pre(fmaf(xv, wC.z, bC.z)), tanh_pre(fmaf(xv, wC.w, bC.w)));
        a1.u[2] = pack2_bf16(tanh_pre(fmaf(xv, wD.x, bD.x)), tanh_pre(fmaf(xv, wD.y, bD.y)));
        a1.u[3] = pack2_bf16(tanh_pre(fmaf(xv, wD.z, bD.z)), tanh_pre(fmaf(xv, wD.w, bD.w)));

#pragma unroll
        for (int nt = 0; nt < 4; ++nt)
            acc[nt] = __builtin_amdgcn_mfma_f32_16x16x32_bf16(a0.s, bf[nt], acc[nt], 0, 0, 0);
#pragma unroll
        for (int nt = 0; nt < 4; ++nt)
            acc[nt] = __builtin_amdgcn_mfma_f32_16x16x32_bf16(a1.s, bf[4 + nt], acc[nt], 0, 0, 0);
    }

    // epilogue: out[b] = bg2 + sum_n Wg2[n] * tanh(C[b,n] + cg[n])   (cg includes bg1)
    float wg2v[4], cgv[4];
#pragma unroll
    for (int nt = 0; nt < 4; ++nt) {
        wg2v[nt] = Wg2[nt * 16 + lm];
        cgv[nt]  = cg[nt * 16 + lm];
    }
    const float bg2 = bg2f[0];
#pragma unroll
    for (int r = 0; r < 4; ++r) {
        float s = 0.f;
#pragma unroll
        for (int nt = 0; nt < 4; ++nt)
            s += wg2v[nt] * fast_tanh(acc[nt][r] + cgv[nt]);
        s += __shfl_xor(s, 1, 64);
        s += __shfl_xor(s, 2, 64);
        s += __shfl_xor(s, 4, 64);
        s += __shfl_xor(s, 8, 64);
        if (lm == 0) {
            int row = rowbase + wave * 16 + quad * 4 + r;
            out[row] = s + bg2;
        }
    }
}

extern "C" void kernel_launch(void* const* d_in, const int* in_sizes, int n_in,
                              void* d_out, int out_size, void* d_ws, size_t ws_size,
                              hipStream_t stream) {
    const float* x   = (const float*)d_in[0];
    const float* W1  = (const float*)d_in[1];
    const float* b1  = (const float*)d_in[2];
    const float* W2  = (const float*)d_in[3];
    const float* b2  = (const float*)d_in[4];
    const float* Wg1 = (const float*)d_in[5];
    const float* bg1 = (const float*)d_in[6];
    const float* Wg2 = (const float*)d_in[7];
    const float* bg2 = (const float*)d_in[8];
    float* out = (float*)d_out;

    // ws budget: 512KB (Bp) + 256B (cg) -- identical to round-1-proven usage
    uint16_t* Bp = (uint16_t*)d_ws;
    float* cg    = (float*)((char*)d_ws + 4096 * 64 * 2);

    kol_pack<<<64, 512, 0, stream>>>(W2, Wg1, Bp);
    kol_cg<<<1, 1024, 0, stream>>>(b2, Wg1, bg1, cg);
    kol_main<<<BATCH / 128, 512, 0, stream>>>(x, W1, b1, Bp, cg, Wg2, bg2, out);
}

// Round 5
// 129.770 us; speedup vs baseline: 1.5052x; 1.1607x over previous
//
#include <hip/hip_runtime.h>
#include <stdint.h>

#define BATCH 32768
#define TANH_C 2.8853900817779268f   // 2/ln(2)

typedef __attribute__((ext_vector_type(8))) short short8;
typedef __attribute__((ext_vector_type(4))) float f32x4;
typedef __attribute__((ext_vector_type(4))) unsigned int u32x4;

__device__ __forceinline__ uint16_t bf16_rtne(float f) {
    union { float f; uint32_t u; } v; v.f = f;
    uint32_t u = v.u;
    u += 0x7fffu + ((u >> 16) & 1u);
    return (uint16_t)(u >> 16);
}

#if defined(__has_builtin)
#if __has_builtin(__builtin_amdgcn_cvt_pk_bf16_f32)
#define HAVE_CVT_PK_BF16 1
#endif
#endif

__device__ __forceinline__ uint32_t pack2_bf16(float a, float b) {
#ifdef HAVE_CVT_PK_BF16
    auto v = __builtin_amdgcn_cvt_pk_bf16_f32(a, b);
    uint32_t r; __builtin_memcpy(&r, &v, 4); return r;
#else
    return (uint32_t)bf16_rtne(a) | ((uint32_t)bf16_rtne(b) << 16);
#endif
}

// input already scaled by TANH_C: tanh(x) with a = TANH_C*x
__device__ __forceinline__ float tanh_pre(float a) {
    float e = __builtin_amdgcn_exp2f(a);
    return 1.0f - 2.0f * __builtin_amdgcn_rcpf(1.0f + e);
}

__device__ __forceinline__ float fast_tanh(float x) {
    return tanh_pre(x * TANH_C);
}

// ---------- kernel P: per-feature-d pack of B = W2g (bf16, MFMA frag order) ----------
// Also emits cgpart[d][n] = sum_o b2[d,o]*Wg1[d*64+o,n] into scratch (d_out reused).
__global__ __launch_bounds__(512) void kol_pack(const float* __restrict__ W2,
                                                const float* __restrict__ Wg1,
                                                const float* __restrict__ b2,
                                                uint16_t* __restrict__ Bp,
                                                float* __restrict__ cgpart) {
    __shared__ __align__(16) float w2t[64 * 65];  // [o][j], stride 65
    __shared__ __align__(16) float g1s[64 * 64];  // [o][n]

    const int t = threadIdx.x;
    const int d = blockIdx.x;

    for (int f = t * 4; f < 4096; f += 2048) {
        float4 v = *(const float4*)&W2[(size_t)d * 4096 + f];
        int j = f >> 6, o = f & 63;   // W2[d][j][o..o+3]
        w2t[(o + 0) * 65 + j] = v.x;
        w2t[(o + 1) * 65 + j] = v.y;
        w2t[(o + 2) * 65 + j] = v.z;
        w2t[(o + 3) * 65 + j] = v.w;
        *(float4*)&g1s[f] = *(const float4*)&Wg1[(size_t)d * 4096 + f];
    }
    __syncthreads();

    const int jg = t >> 6;   // wave index = j-octet, wave-uniform
    const int n  = t & 63;
    float acc[8];
#pragma unroll
    for (int i = 0; i < 8; ++i) acc[i] = 0.f;

#pragma unroll 4
    for (int o = 0; o < 64; ++o) {
        float g = g1s[o * 64 + n];                 // 2-way alias = free
        const float* w = &w2t[o * 65 + jg * 8];    // wave-uniform broadcast
#pragma unroll
        for (int jj = 0; jj < 8; ++jj) acc[jj] = fmaf(w[jj], g, acc[jj]);
    }

    u32x4 pk;
    pk.x = pack2_bf16(acc[0], acc[1]);
    pk.y = pack2_bf16(acc[2], acc[3]);
    pk.z = pack2_bf16(acc[4], acc[5]);
    pk.w = pack2_bf16(acc[6], acc[7]);
    int off = ((d * 2 + (jg >> 2)) * 4 + (n >> 4)) * 64 + (jg & 3) * 16 + (n & 15);
    ((u32x4*)Bp)[off] = pk;   // contiguous 256B per 16-lane group

    // cg partial for this d: wave 0 only (b2[d*64+o] is wave-uniform -> s_load)
    if (t < 64) {
        float a = 0.f;
        const float* b2d = &b2[(size_t)d * 64];
#pragma unroll 4
        for (int o = 0; o < 64; ++o)
            a = fmaf(b2d[o], g1s[o * 64 + t], a);
        cgpart[d * 64 + t] = a;
    }
}

// ---------- kernel R: cg[n] = bg1[n] + sum_d cgpart[d][n]  (deterministic, tiny) ----------
__global__ __launch_bounds__(256) void kol_reduce_cg(const float* __restrict__ cgpart,
                                                     const float* __restrict__ bg1,
                                                     float* __restrict__ cg) {
    __shared__ float red[4][64];
    const int t = threadIdx.x;
    const int n = t & 63, seg = t >> 6;
    float a = 0.f;
#pragma unroll 4
    for (int d = seg * 16; d < seg * 16 + 16; ++d)
        a += cgpart[d * 64 + n];
    red[seg][n] = a;
    __syncthreads();
    if (t < 64)
        cg[n] = bg1[n] + red[0][n] + red[1][n] + red[2][n] + red[3][n];
}

// ---------- kernel M: main fused GEMM, no K-loop barriers, B prefetched 1 iter ahead ----
__global__ __launch_bounds__(512, 2) void kol_main(
    const float* __restrict__ x, const float* __restrict__ W1, const float* __restrict__ b1,
    const uint16_t* __restrict__ Bp, const float* __restrict__ cg,
    const float* __restrict__ Wg2, const float* __restrict__ bg2f,
    float* __restrict__ out) {
    __shared__ __align__(16) float xs[128 * 68];   // pre-scaled x, stride 68
    __shared__ __align__(16) float w1s[4096];
    __shared__ __align__(16) float b1s[4096];      // pre-scaled by TANH_C

    const int tid = threadIdx.x;
    const int wave = tid >> 6, lane = tid & 63;
    const int quad = lane >> 4, lm = lane & 15;
    const int rowbase = blockIdx.x * 128;

    for (int f = tid * 4; f < 8192; f += 2048) {
        int r = f >> 6, c = f & 63;
        float4 v = *(const float4*)&x[(size_t)(rowbase + r) * 64 + c];
        v.x *= TANH_C; v.y *= TANH_C; v.z *= TANH_C; v.w *= TANH_C;
        *(float4*)&xs[r * 68 + c] = v;
    }
    for (int f = tid * 4; f < 4096; f += 2048) {
        *(float4*)&w1s[f] = *(const float4*)&W1[f];
        float4 b = *(const float4*)&b1[f];
        b.x *= TANH_C; b.y *= TANH_C; b.z *= TANH_C; b.w *= TANH_C;
        *(float4*)&b1s[f] = b;
    }
    __syncthreads();   // the ONLY barrier

    f32x4 acc[4];
#pragma unroll
    for (int nt = 0; nt < 4; ++nt) acc[nt] = (f32x4){0.f, 0.f, 0.f, 0.f};

    const int myrow = wave * 16 + lm;
    const float* xrow = &xs[myrow * 68];
    const short8* bbase = (const short8*)Bp + lane;   // fragment stream, 16B/lane

    // prime the pipeline with d=0's 8 B-fragments
    short8 bf[8];
#pragma unroll
    for (int i = 0; i < 8; ++i) bf[i] = bbase[i * 64];

#pragma unroll 2
    for (int d = 0; d < 64; ++d) {
        // prefetch next iteration's B fragments (wraps to d=0 on last iter; unused)
        short8 bn[8];
        const short8* bpn = bbase + (size_t)((d + 1) & 63) * 512;
#pragma unroll
        for (int i = 0; i < 8; ++i) bn[i] = bpn[i * 64];

        // A fragments: 16 tanh in registers while prefetch is in flight
        const float xv = xrow[d];
        const float* wq = &w1s[d * 64 + quad * 8];
        const float* bq = &b1s[d * 64 + quad * 8];
        float4 wA = *(const float4*)&wq[0];
        float4 wB = *(const float4*)&wq[4];
        float4 wC = *(const float4*)&wq[32];
        float4 wD = *(const float4*)&wq[36];
        float4 bA = *(const float4*)&bq[0];
        float4 bB = *(const float4*)&bq[4];
        float4 bC = *(const float4*)&bq[32];
        float4 bD = *(const float4*)&bq[36];

        union { short8 s; uint32_t u[4]; } a0, a1;
        a0.u[0] = pack2_bf16(tanh_pre(fmaf(xv, wA.x, bA.x)), tanh_pre(fmaf(xv, wA.y, bA.y)));
        a0.u[1] = pack2_bf16(tanh_pre(fmaf(xv, wA.z, bA.z)), tanh_pre(fmaf(xv, wA.w, bA.w)));
        a0.u[2] = pack2_bf16(tanh_pre(fmaf(xv, wB.x, bB.x)), tanh_pre(fmaf(xv, wB.y, bB.y)));
        a0.u[3] = pack2_bf16(tanh_pre(fmaf(xv, wB.z, bB.z)), tanh_pre(fmaf(xv, wB.w, bB.w)));
        a1.u[0] = pack2_bf16(tanh_pre(fmaf(xv, wC.x, bC.x)), tanh_pre(fmaf(xv, wC.y, bC.y)));
        a1.u[1] = pack2_bf16(tanh_pre(fmaf(xv, wC.z, bC.z)), tanh_pre(fmaf(xv, wC.w, bC.w)));
        a1.u[2] = pack2_bf16(tanh_pre(fmaf(xv, wD.x, bD.x)), tanh_pre(fmaf(xv, wD.y, bD.y)));
        a1.u[3] = pack2_bf16(tanh_pre(fmaf(xv, wD.z, bD.z)), tanh_pre(fmaf(xv, wD.w, bD.w)));

#pragma unroll
        for (int nt = 0; nt < 4; ++nt)
            acc[nt] = __builtin_amdgcn_mfma_f32_16x16x32_bf16(a0.s, bf[nt], acc[nt], 0, 0, 0);
#pragma unroll
        for (int nt = 0; nt < 4; ++nt)
            acc[nt] = __builtin_amdgcn_mfma_f32_16x16x32_bf16(a1.s, bf[4 + nt], acc[nt], 0, 0, 0);

#pragma unroll
        for (int i = 0; i < 8; ++i) bf[i] = bn[i];
    }

    // epilogue: out[b] = bg2 + sum_n Wg2[n] * tanh(C[b,n] + cg[n])   (cg includes bg1)
    float wg2v[4], cgv[4];
#pragma unroll
    for (int nt = 0; nt < 4; ++nt) {
        wg2v[nt] = Wg2[nt * 16 + lm];
        cgv[nt]  = cg[nt * 16 + lm];
    }
    const float bg2 = bg2f[0];
#pragma unroll
    for (int r = 0; r < 4; ++r) {
        float s = 0.f;
#pragma unroll
        for (int nt = 0; nt < 4; ++nt)
            s += wg2v[nt] * fast_tanh(acc[nt][r] + cgv[nt]);
        s += __shfl_xor(s, 1, 64);
        s += __shfl_xor(s, 2, 64);
        s += __shfl_xor(s, 4, 64);
        s += __shfl_xor(s, 8, 64);
        if (lm == 0) {
            int row = rowbase + wave * 16 + quad * 4 + r;
            out[row] = s + bg2;
        }
    }
}

extern "C" void kernel_launch(void* const* d_in, const int* in_sizes, int n_in,
                              void* d_out, int out_size, void* d_ws, size_t ws_size,
                              hipStream_t stream) {
    const float* x   = (const float*)d_in[0];
    const float* W1  = (const float*)d_in[1];
    const float* b1  = (const float*)d_in[2];
    const float* W2  = (const float*)d_in[3];
    const float* b2  = (const float*)d_in[4];
    const float* Wg1 = (const float*)d_in[5];
    const float* bg1 = (const float*)d_in[6];
    const float* Wg2 = (const float*)d_in[7];
    const float* bg2 = (const float*)d_in[8];
    float* out = (float*)d_out;

    // ws: 512KB (Bp) + 256B (cg). cgpart scratch (16KB) lives in d_out (128KB),
    // written by kol_pack, consumed by kol_reduce_cg, then fully overwritten by kol_main.
    uint16_t* Bp   = (uint16_t*)d_ws;
    float* cg      = (float*)((char*)d_ws + 4096 * 64 * 2);
    float* cgpart  = out;

    kol_pack<<<64, 512, 0, stream>>>(W2, Wg1, b2, Bp, cgpart);
    kol_reduce_cg<<<1, 256, 0, stream>>>(cgpart, bg1, cg);
    kol_main<<<BATCH / 128, 512, 0, stream>>>(x, W1, b1, Bp, cg, Wg2, bg2, out);
}